// Round 15
// baseline (167.103 us; speedup 1.0000x reference)
//
#include <hip/hip_runtime.h>
#include <math.h>

#define BB 16
#define NN 4096
#define DD 128
#define KK 1024
#define NPTS (BB*NN)

typedef _Float16 half8 __attribute__((ext_vector_type(8)));
typedef float f32x4 __attribute__((ext_vector_type(4)));

static __device__ __forceinline__ uint pack2(float a, float b) {
    _Float16 ha = (_Float16)a, hb = (_Float16)b;
    unsigned short ua = __builtin_bit_cast(unsigned short, ha);
    unsigned short ub = __builtin_bit_cast(unsigned short, hb);
    return (uint)ua | ((uint)ub << 16);
}

typedef __attribute__((address_space(1))) const void as1_void;
typedef __attribute__((address_space(3))) void as3_void;
static __device__ __forceinline__ void gld16(const void* g, void* l) {
    // async global->LDS, 16B/lane; LDS dest = uniform base + lane*16 (HW rule)
    __builtin_amdgcn_global_load_lds((as1_void*)g, (as3_void*)l, 16, 0, 0);
}

#define VMWAIT0 asm volatile("s_waitcnt vmcnt(0)" ::: "memory")
#define LGKM0   asm volatile("s_waitcnt lgkmcnt(0)" ::: "memory")
#define RBARRIER do { __builtin_amdgcn_s_barrier(); asm volatile("" ::: "memory"); } while (0)
#define SCHEDB  __builtin_amdgcn_sched_barrier(0)

// ---------------- kernel 0 (fused): centroid fragments + squared norms ----------------
// Blocks [0,64): pre-permute centroids into 16x16x32 B-fragment order
//   fragment (nt, c, lane) = cent row (nt*16 + (lane&15)), d in [c*32+(lane>>4)*8, +8),
//   split fp16 hi + (lo*1024), packed uint4 (HW-verified layout, R12-R14 pass).
// Blocks [64,320): cn[row] = ||c_row||^2 in double (wave per row).
__global__ void prep_kernel(const float* __restrict__ cent,
                            uint4* __restrict__ cfh, uint4* __restrict__ cfl,
                            float* __restrict__ cnorm) {
    if (blockIdx.x < 64) {
        const int gid = blockIdx.x * 256 + threadIdx.x;   // [0, 64*4*64) = 16384
        const int nt = gid >> 8;
        const int c = (gid >> 6) & 3;
        const int lane = gid & 63;
        const int row = nt * 16 + (lane & 15);
        const int d0 = c * 32 + (lane >> 4) * 8;
        const float* src = cent + (size_t)row * DD + d0;
        float v[8];
#pragma unroll
        for (int i = 0; i < 8; ++i) v[i] = src[i];
        float lo[8];
#pragma unroll
        for (int i = 0; i < 8; ++i) {
            _Float16 h = (_Float16)v[i];
            lo[i] = (v[i] - (float)h) * 1024.f;
        }
        uint4 h4, l4;
        h4.x = pack2(v[0], v[1]); h4.y = pack2(v[2], v[3]);
        h4.z = pack2(v[4], v[5]); h4.w = pack2(v[6], v[7]);
        l4.x = pack2(lo[0], lo[1]); l4.y = pack2(lo[2], lo[3]);
        l4.z = pack2(lo[4], lo[5]); l4.w = pack2(lo[6], lo[7]);
        cfh[gid] = h4;
        cfl[gid] = l4;
    } else {
        const int w = threadIdx.x >> 6, lane = threadIdx.x & 63;
        const int row = (blockIdx.x - 64) * 4 + w;
        float2 v = ((const float2*)(cent + (size_t)row * DD))[lane];
        double s = (double)v.x * v.x + (double)v.y * v.y;
#pragma unroll
        for (int m = 1; m < 64; m <<= 1) s += __shfl_xor(s, m);
        if (lane == 0) cnorm[row] = (float)s;
    }
}

// ---------------- kernel 1: nearest-centroid, 16x16x32 MFMA, 8 waves/SIMD ----------------
// 2048 blocks x 4 waves; block = (pblk = bid>>1, kh = bid&1). Wave w owns points
// [pblk*64 + w*16, +16); block scans the 32 16-cent tiles of k-half kh.
// LDS = 2-slot ring (16KB) + cnS half (2KB) = 18KB -> 8 blocks/CU resident
// (grid 2048 = 8/CU) = 32 waves/CU = 8 waves/SIMD. VGPR <= 64 (R14 compiled 52).
// Protocol: phase t reads slot t&1 (stage t), issues stage t+1 into slot^1
// (stage t-1's readers all passed the previous barrier), then vmcnt(0)+barrier.
// The per-wave drain is covered by the 7 other waves/SIMD (TLP), which is the
// lever R6-R14 lacked. Phase body: R14's merged-cr + zero4 + chunked reads.
__launch_bounds__(256, 8)
__global__ void assign_mfma11(const float* __restrict__ x,
                              const uint4* __restrict__ cfh, const uint4* __restrict__ cfl,
                              const float* __restrict__ cn,
                              float* __restrict__ bestv, int* __restrict__ bkv,
                              float* __restrict__ xn_arr) {
    __shared__ uint4 ring[2][8][64];   // [slot][frag-row: 0-3 hi(c), 4-7 lo(c)][lane]
    __shared__ float cnS[KK / 2];

    const int tid = threadIdx.x;
    const int lane = tid & 63;
    const int w = tid >> 6;
    const int l15 = lane & 15;
    const int lg = lane >> 4;          // k-group 0..3
    const int kh = blockIdx.x & 1;
    const int pblk = blockIdx.x >> 1;
    const int p0 = pblk * 64 + w * 16;

#define STAGE_ISSUE(S)                                                              \
    { const int s_ = (S); const int sl_ = s_ & 1;                                   \
      const size_t fb_ = ((size_t)(kh * 32 + s_) * 4 + w) * 64 + lane;              \
      gld16(cfh + fb_, &ring[sl_][w][0]);                                           \
      gld16(cfl + fb_, &ring[sl_][w + 4][0]); }

    // prologue: issue stage 0 first (flies under the cn/x loads)
    STAGE_ISSUE(0)

    // this half's cn -> LDS (512 floats; consumed in epilogues)
    ((float2*)cnS)[tid] = ((const float2*)(cn + kh * (KK / 2)))[tid];

    // A fragments: lane covers row l15, k = c*32 + lg*8 + i (same split as R3-R14)
    half8 ahi[4], alo[4];
    float xs = 0.f;
    const float4* xrow = (const float4*)(x + (size_t)(p0 + l15) * DD);
#pragma unroll
    for (int c = 0; c < 4; ++c) {
        float4 v0 = xrow[c * 8 + lg * 2];
        float4 v1 = xrow[c * 8 + lg * 2 + 1];
        float vv[8] = {v0.x, v0.y, v0.z, v0.w, v1.x, v1.y, v1.z, v1.w};
#pragma unroll
        for (int i = 0; i < 8; ++i) {
            _Float16 h = (_Float16)vv[i];
            ahi[c][i] = h;
            alo[c][i] = (_Float16)((vv[i] - (float)h) * 1024.f);
            xs = fmaf(vv[i], vv[i], xs);
        }
    }
    // lanes {l15, l15+16, l15+32, l15+48} hold disjoint k-quarters of row l15
    xs += __shfl_xor(xs, 16);
    xs += __shfl_xor(xs, 32);          // every lane: ||x_{l15}||^2

    float best[4];
    int bk[4];
#pragma unroll
    for (int r = 0; r < 4; ++r) { best[r] = INFINITY; bk[r] = 0; }

    f32x4 zero4;                       // persistent zero C-in for MFMA chain heads
#pragma unroll
    for (int i = 0; i < 4; ++i) zero4[i] = 0.f;

    VMWAIT0;    // stage 0 + x + cn loads all landed
    LGKM0;      // own cnS ds_write done
    RBARRIER;   // all waves: stage 0 + cnS visible
    SCHEDB;

#define DO_PHASE(NT, DOSTG, WAITSEQ)                                                \
    {                                                                               \
        const int sl_ = (NT) & 1;                                                   \
        /* chunk 1: hi fragments -> hh chain + alo*bh half of cr (R13/R14 order) */ \
        uint4 b0 = ring[sl_][0][lane], b1 = ring[sl_][1][lane];                     \
        uint4 b2 = ring[sl_][2][lane], b3 = ring[sl_][3][lane];                     \
        if (DOSTG) STAGE_ISSUE((NT) + 1)                                            \
        f32x4 hh, cr;                                                               \
        __builtin_amdgcn_s_setprio(1);                                              \
        hh = __builtin_amdgcn_mfma_f32_16x16x32_f16(ahi[0], __builtin_bit_cast(half8, b0), zero4, 0, 0, 0); \
        cr = __builtin_amdgcn_mfma_f32_16x16x32_f16(alo[0], __builtin_bit_cast(half8, b0), zero4, 0, 0, 0); \
        hh = __builtin_amdgcn_mfma_f32_16x16x32_f16(ahi[1], __builtin_bit_cast(half8, b1), hh, 0, 0, 0);    \
        cr = __builtin_amdgcn_mfma_f32_16x16x32_f16(alo[1], __builtin_bit_cast(half8, b1), cr, 0, 0, 0);    \
        hh = __builtin_amdgcn_mfma_f32_16x16x32_f16(ahi[2], __builtin_bit_cast(half8, b2), hh, 0, 0, 0);    \
        cr = __builtin_amdgcn_mfma_f32_16x16x32_f16(alo[2], __builtin_bit_cast(half8, b2), cr, 0, 0, 0);    \
        hh = __builtin_amdgcn_mfma_f32_16x16x32_f16(ahi[3], __builtin_bit_cast(half8, b3), hh, 0, 0, 0);    \
        cr = __builtin_amdgcn_mfma_f32_16x16x32_f16(alo[3], __builtin_bit_cast(half8, b3), cr, 0, 0, 0);    \
        __builtin_amdgcn_s_setprio(0);                                              \
        /* chunk 2: lo fragments (reuse b0..b3) -> ahi*bl half of cr */             \
        b0 = ring[sl_][4][lane]; b1 = ring[sl_][5][lane];                           \
        b2 = ring[sl_][6][lane]; b3 = ring[sl_][7][lane];                           \
        __builtin_amdgcn_s_setprio(1);                                              \
        cr = __builtin_amdgcn_mfma_f32_16x16x32_f16(ahi[0], __builtin_bit_cast(half8, b0), cr, 0, 0, 0);    \
        cr = __builtin_amdgcn_mfma_f32_16x16x32_f16(ahi[1], __builtin_bit_cast(half8, b1), cr, 0, 0, 0);    \
        cr = __builtin_amdgcn_mfma_f32_16x16x32_f16(ahi[2], __builtin_bit_cast(half8, b2), cr, 0, 0, 0);    \
        cr = __builtin_amdgcn_mfma_f32_16x16x32_f16(ahi[3], __builtin_bit_cast(half8, b3), cr, 0, 0, 0);    \
        __builtin_amdgcn_s_setprio(0);                                              \
        {   const float cnv_ = cnS[(NT) * 16 + l15];                                \
            const int kcur_ = (kh * 32 + (NT)) * 16 + l15;                          \
            _Pragma("unroll")                                                       \
            for (int r = 0; r < 4; ++r) {                                           \
                float v_ = cnv_ - 2.f * hh[r] - 0.001953125f * cr[r];               \
                if (v_ < best[r]) { best[r] = v_; bk[r] = kcur_; }                  \
            }                                                                       \
        }                                                                           \
        WAITSEQ;                                                                    \
    }

#define W0B do { VMWAIT0; RBARRIER; SCHEDB; } while (0)
#define WN do { } while (0)

#pragma unroll 1
    for (int t = 0; t < 31; ++t) {
        DO_PHASE(t, 1, W0B)
    }
    DO_PHASE(31, 0, WN)   // last tile: no staging, no trailing barrier
#undef DO_PHASE
#undef STAGE_ISSUE
#undef W0B
#undef WN

    // argmin across the 16 centroid-columns within each 16-lane group
    // (masks < 16 keep lg fixed); numpy tie-break: smaller k
#pragma unroll
    for (int r = 0; r < 4; ++r) {
        float bv = best[r]; int bi = bk[r];
#pragma unroll
        for (int m = 1; m < 16; m <<= 1) {
            float ov = __shfl_xor(bv, m);
            int oi = __shfl_xor(bi, m);
            if (ov < bv || (ov == bv && oi < bi)) { bv = ov; bi = oi; }
        }
        best[r] = bv; bk[r] = bi;
    }

    // D layout (m89-verified): col = lane&15, row = (lane>>4)*4 + r
    float xnv[4];
#pragma unroll
    for (int r = 0; r < 4; ++r)
        xnv[r] = __shfl(xs, lg * 4 + r);   // xs of point (lg*4+r) lives in lane (lg*4+r)

    if (l15 == 0) {
#pragma unroll
        for (int r = 0; r < 4; ++r) {
            int p = p0 + lg * 4 + r;
            bestv[(size_t)kh * NPTS + p] = best[r];    // pre-xn partial min
            bkv[(size_t)kh * NPTS + p] = bk[r];
            if (kh == 0) xn_arr[p] = xnv[r];
        }
    }
}

// ---------------- kernel 2: merge halves + per-batch stats + histogram + normalize ----------------
__global__ void finalize_kernel(const float* __restrict__ bestv, const int* __restrict__ bkv,
                                const float* __restrict__ xn_arr,
                                const float* __restrict__ weights, float* __restrict__ out) {
    __shared__ float dS[NN];      // merged min distances
    __shared__ int   bkS[NN];     // merged argmin
    __shared__ float red[1024];
    __shared__ int hist[KK];
    __shared__ float bc[2];       // mean, thr
    const int b = blockIdx.x;
    const int tid = threadIdx.x;

    // merge the two k-halves (strict <: half-0 ks all smaller -> numpy first-min),
    // then sq = xn + best, d = sqrt(max(sq,0))  — R9/R13-validated arithmetic order.
    float s = 0.f;
#pragma unroll
    for (int j = 0; j < NN / 1024; ++j) {
        int i = tid + 1024 * j;
        size_t gi = (size_t)b * NN + i;
        float b0 = bestv[gi], b1 = bestv[NPTS + gi];
        int k0 = bkv[gi], k1 = bkv[NPTS + gi];
        float bm = b0; int km = k0;
        if (b1 < bm) { bm = b1; km = k1; }
        float d = sqrtf(fmaxf(xn_arr[gi] + bm, 0.f));
        dS[i] = d; bkS[i] = km;
        s += d;
    }

    // pass A: mean (two-pass std to match numpy numerics)
    red[tid] = s;
    __syncthreads();
    for (int off = 512; off > 0; off >>= 1) {
        if (tid < off) red[tid] += red[tid + off];
        __syncthreads();
    }
    if (tid == 0) bc[0] = red[0] / (float)NN;
    __syncthreads();
    const float mean = bc[0];

    // pass B: sum of squared deviations -> thr = mean + std(ddof=1)
    float ss = 0.f;
#pragma unroll
    for (int j = 0; j < NN / 1024; ++j) {
        float v = dS[tid + 1024 * j] - mean;
        ss += v * v;
    }
    red[tid] = ss;
    __syncthreads();
    for (int off = 512; off > 0; off >>= 1) {
        if (tid < off) red[tid] += red[tid + off];
        __syncthreads();
    }
    if (tid == 0) bc[1] = mean + sqrtf(red[0] / (float)(NN - 1));

    // histogram of masked assignments
    hist[tid] = 0;
    __syncthreads();
    const float thr = bc[1];
#pragma unroll
    for (int j = 0; j < NN / 1024; ++j) {
        int i = tid + 1024 * j;
        if (dS[i] < thr) atomicAdd(&hist[bkS[i]], 1);
    }
    __syncthreads();

    // asmk = counts*weights; L2-normalize the row (one k per thread)
    const float a = (float)hist[tid] * weights[tid];
    red[tid] = a * a;
    __syncthreads();
    for (int off = 512; off > 0; off >>= 1) {
        if (tid < off) red[tid] += red[tid + off];
        __syncthreads();
    }
    const float norm = sqrtf(red[0]);
    const float scale = 1.f / fmaxf(norm, 1e-12f);
    out[(size_t)b * KK + tid] = a * scale;
}

extern "C" void kernel_launch(void* const* d_in, const int* in_sizes, int n_in,
                              void* d_out, int out_size, void* d_ws, size_t ws_size,
                              hipStream_t stream) {
    const float* x = (const float*)d_in[0];
    const float* cent = (const float*)d_in[1];
    const float* weights = (const float*)d_in[2];
    float* out = (float*)d_out;

    char* ws = (char*)d_ws;
    float* bestv  = (float*)(ws + 0);          // [2][NPTS]  512 KB
    int*   bkv    = (int*)  (ws + 524288);     // [2][NPTS]  512 KB
    float* xn_arr = (float*)(ws + 1048576);    // [NPTS]     256 KB
    float* cn     = (float*)(ws + 1310720);    // [KK]         4 KB
    uint4* cfh    = (uint4*)(ws + 1314816);    // 256 KB
    uint4* cfl    = (uint4*)(ws + 1576960);    // 256 KB

    prep_kernel<<<320, 256, 0, stream>>>(cent, cfh, cfl, cn);
    assign_mfma11<<<NPTS / 32, 256, 0, stream>>>(x, cfh, cfl, cn, bestv, bkv, xn_arr);
    finalize_kernel<<<BB, 1024, 0, stream>>>(bestv, bkv, xn_arr, weights, out);
}

// Round 16
// 77.544 us; speedup vs baseline: 2.1550x; 2.1550x over previous
//
#include <hip/hip_runtime.h>
#include <math.h>

#define BB 16
#define NN 4096
#define DD 128
#define KK 1024
#define NPTS (BB*NN)

typedef _Float16 half8 __attribute__((ext_vector_type(8)));
typedef float f32x4 __attribute__((ext_vector_type(4)));

static __device__ __forceinline__ uint pack2(float a, float b) {
    _Float16 ha = (_Float16)a, hb = (_Float16)b;
    unsigned short ua = __builtin_bit_cast(unsigned short, ha);
    unsigned short ub = __builtin_bit_cast(unsigned short, hb);
    return (uint)ua | ((uint)ub << 16);
}

typedef __attribute__((address_space(1))) const void as1_void;
typedef __attribute__((address_space(3))) void as3_void;
static __device__ __forceinline__ void gld16(const void* g, void* l) {
    // async global->LDS, 16B/lane; LDS dest = uniform base + lane*16 (HW rule)
    __builtin_amdgcn_global_load_lds((as1_void*)g, (as3_void*)l, 16, 0, 0);
}

#define VMWAIT0 asm volatile("s_waitcnt vmcnt(0)" ::: "memory")
#define LGKM0   asm volatile("s_waitcnt lgkmcnt(0)" ::: "memory")
#define RBARRIER do { __builtin_amdgcn_s_barrier(); asm volatile("" ::: "memory"); } while (0)
#define SCHEDB  __builtin_amdgcn_sched_barrier(0)

// ---------------- kernel 0 (fused): centroid fragments + squared norms ----------------
// Blocks [0,64): pre-permute centroids into 16x16x32 B-fragment order
//   fragment (nt, c, lane) = cent row (nt*16 + (lane&15)), d in [c*32+(lane>>4)*8, +8),
//   split fp16 hi + (lo*1024), packed uint4 (HW-verified layout, R12-R15 pass).
// Blocks [64,320): cn[row] = ||c_row||^2 in double (wave per row).
__global__ void prep_kernel(const float* __restrict__ cent,
                            uint4* __restrict__ cfh, uint4* __restrict__ cfl,
                            float* __restrict__ cnorm) {
    if (blockIdx.x < 64) {
        const int gid = blockIdx.x * 256 + threadIdx.x;   // [0, 64*4*64) = 16384
        const int nt = gid >> 8;
        const int c = (gid >> 6) & 3;
        const int lane = gid & 63;
        const int row = nt * 16 + (lane & 15);
        const int d0 = c * 32 + (lane >> 4) * 8;
        const float* src = cent + (size_t)row * DD + d0;
        float v[8];
#pragma unroll
        for (int i = 0; i < 8; ++i) v[i] = src[i];
        float lo[8];
#pragma unroll
        for (int i = 0; i < 8; ++i) {
            _Float16 h = (_Float16)v[i];
            lo[i] = (v[i] - (float)h) * 1024.f;
        }
        uint4 h4, l4;
        h4.x = pack2(v[0], v[1]); h4.y = pack2(v[2], v[3]);
        h4.z = pack2(v[4], v[5]); h4.w = pack2(v[6], v[7]);
        l4.x = pack2(lo[0], lo[1]); l4.y = pack2(lo[2], lo[3]);
        l4.z = pack2(lo[4], lo[5]); l4.w = pack2(lo[6], lo[7]);
        cfh[gid] = h4;
        cfl[gid] = l4;
    } else {
        const int w = threadIdx.x >> 6, lane = threadIdx.x & 63;
        const int row = (blockIdx.x - 64) * 4 + w;
        float2 v = ((const float2*)(cent + (size_t)row * DD))[lane];
        double s = (double)v.x * v.x + (double)v.y * v.y;
#pragma unroll
        for (int m = 1; m < 64; m <<= 1) s += __shfl_xor(s, m);
        if (lane == 0) cnorm[row] = (float)s;
    }
}

// ---------------- kernel 1: nearest-centroid, 16x16x32 MFMA, natural 8 waves/SIMD ----------------
// 2048 blocks x 4 waves; block = (pblk = bid>>1, kh = bid&1). Wave w owns points
// [pblk*64 + w*16, +16); block scans the 32 16-cent tiles of k-half kh.
// LDS = 2-slot ring (16KB) + cnS half (2KB) = 18KB -> 8 blocks/CU resident.
// launch_bounds (256,4): cap 128 >> live set (~52, R14 evidence) -> NO forced
// spill (R15's (256,8) pinned the allocator to 64 and it spilled 44MB/dispatch).
// If natural allocation lands <= 64 VGPR (R14: 52), the HW occupancy quantum
// grants 8 waves/SIMD anyway -> the TLP test R15 was meant to run.
// Protocol: phase t reads slot t&1 (stage t), issues stage t+1 into slot^1,
// then vmcnt(0)+barrier; per-wave drain covered by 7 other waves/SIMD.
__launch_bounds__(256, 4)
__global__ void assign_mfma11(const float* __restrict__ x,
                              const uint4* __restrict__ cfh, const uint4* __restrict__ cfl,
                              const float* __restrict__ cn,
                              float* __restrict__ bestv, int* __restrict__ bkv,
                              float* __restrict__ xn_arr) {
    __shared__ uint4 ring[2][8][64];   // [slot][frag-row: 0-3 hi(c), 4-7 lo(c)][lane]
    __shared__ float cnS[KK / 2];

    const int tid = threadIdx.x;
    const int lane = tid & 63;
    const int w = tid >> 6;
    const int l15 = lane & 15;
    const int lg = lane >> 4;          // k-group 0..3
    const int kh = blockIdx.x & 1;
    const int pblk = blockIdx.x >> 1;
    const int p0 = pblk * 64 + w * 16;

#define STAGE_ISSUE(S)                                                              \
    { const int s_ = (S); const int sl_ = s_ & 1;                                   \
      const size_t fb_ = ((size_t)(kh * 32 + s_) * 4 + w) * 64 + lane;              \
      gld16(cfh + fb_, &ring[sl_][w][0]);                                           \
      gld16(cfl + fb_, &ring[sl_][w + 4][0]); }

    // prologue: issue stage 0 first (flies under the cn/x loads)
    STAGE_ISSUE(0)

    // this half's cn -> LDS (512 floats; consumed in epilogues)
    ((float2*)cnS)[tid] = ((const float2*)(cn + kh * (KK / 2)))[tid];

    // A fragments: lane covers row l15, k = c*32 + lg*8 + i (same split as R3-R15)
    half8 ahi[4], alo[4];
    float xs = 0.f;
    const float4* xrow = (const float4*)(x + (size_t)(p0 + l15) * DD);
#pragma unroll
    for (int c = 0; c < 4; ++c) {
        float4 v0 = xrow[c * 8 + lg * 2];
        float4 v1 = xrow[c * 8 + lg * 2 + 1];
        float vv[8] = {v0.x, v0.y, v0.z, v0.w, v1.x, v1.y, v1.z, v1.w};
#pragma unroll
        for (int i = 0; i < 8; ++i) {
            _Float16 h = (_Float16)vv[i];
            ahi[c][i] = h;
            alo[c][i] = (_Float16)((vv[i] - (float)h) * 1024.f);
            xs = fmaf(vv[i], vv[i], xs);
        }
    }
    // lanes {l15, l15+16, l15+32, l15+48} hold disjoint k-quarters of row l15
    xs += __shfl_xor(xs, 16);
    xs += __shfl_xor(xs, 32);          // every lane: ||x_{l15}||^2

    float best[4];
    int bk[4];
#pragma unroll
    for (int r = 0; r < 4; ++r) { best[r] = INFINITY; bk[r] = 0; }

    f32x4 zero4;                       // persistent zero C-in for MFMA chain heads
#pragma unroll
    for (int i = 0; i < 4; ++i) zero4[i] = 0.f;

    VMWAIT0;    // stage 0 + x + cn loads all landed
    LGKM0;      // own cnS ds_write done
    RBARRIER;   // all waves: stage 0 + cnS visible
    SCHEDB;

#define DO_PHASE(NT, DOSTG, WAITSEQ)                                                \
    {                                                                               \
        const int sl_ = (NT) & 1;                                                   \
        /* chunk 1: hi fragments -> hh chain + alo*bh half of cr (R13/R14 order) */ \
        uint4 b0 = ring[sl_][0][lane], b1 = ring[sl_][1][lane];                     \
        uint4 b2 = ring[sl_][2][lane], b3 = ring[sl_][3][lane];                     \
        if (DOSTG) STAGE_ISSUE((NT) + 1)                                            \
        f32x4 hh, cr;                                                               \
        __builtin_amdgcn_s_setprio(1);                                              \
        hh = __builtin_amdgcn_mfma_f32_16x16x32_f16(ahi[0], __builtin_bit_cast(half8, b0), zero4, 0, 0, 0); \
        cr = __builtin_amdgcn_mfma_f32_16x16x32_f16(alo[0], __builtin_bit_cast(half8, b0), zero4, 0, 0, 0); \
        hh = __builtin_amdgcn_mfma_f32_16x16x32_f16(ahi[1], __builtin_bit_cast(half8, b1), hh, 0, 0, 0);    \
        cr = __builtin_amdgcn_mfma_f32_16x16x32_f16(alo[1], __builtin_bit_cast(half8, b1), cr, 0, 0, 0);    \
        hh = __builtin_amdgcn_mfma_f32_16x16x32_f16(ahi[2], __builtin_bit_cast(half8, b2), hh, 0, 0, 0);    \
        cr = __builtin_amdgcn_mfma_f32_16x16x32_f16(alo[2], __builtin_bit_cast(half8, b2), cr, 0, 0, 0);    \
        hh = __builtin_amdgcn_mfma_f32_16x16x32_f16(ahi[3], __builtin_bit_cast(half8, b3), hh, 0, 0, 0);    \
        cr = __builtin_amdgcn_mfma_f32_16x16x32_f16(alo[3], __builtin_bit_cast(half8, b3), cr, 0, 0, 0);    \
        __builtin_amdgcn_s_setprio(0);                                              \
        /* chunk 2: lo fragments (reuse b0..b3) -> ahi*bl half of cr */             \
        b0 = ring[sl_][4][lane]; b1 = ring[sl_][5][lane];                           \
        b2 = ring[sl_][6][lane]; b3 = ring[sl_][7][lane];                           \
        __builtin_amdgcn_s_setprio(1);                                              \
        cr = __builtin_amdgcn_mfma_f32_16x16x32_f16(ahi[0], __builtin_bit_cast(half8, b0), cr, 0, 0, 0);    \
        cr = __builtin_amdgcn_mfma_f32_16x16x32_f16(ahi[1], __builtin_bit_cast(half8, b1), cr, 0, 0, 0);    \
        cr = __builtin_amdgcn_mfma_f32_16x16x32_f16(ahi[2], __builtin_bit_cast(half8, b2), cr, 0, 0, 0);    \
        cr = __builtin_amdgcn_mfma_f32_16x16x32_f16(ahi[3], __builtin_bit_cast(half8, b3), cr, 0, 0, 0);    \
        __builtin_amdgcn_s_setprio(0);                                              \
        {   const float cnv_ = cnS[(NT) * 16 + l15];                                \
            const int kcur_ = (kh * 32 + (NT)) * 16 + l15;                          \
            _Pragma("unroll")                                                       \
            for (int r = 0; r < 4; ++r) {                                           \
                float v_ = cnv_ - 2.f * hh[r] - 0.001953125f * cr[r];               \
                if (v_ < best[r]) { best[r] = v_; bk[r] = kcur_; }                  \
            }                                                                       \
        }                                                                           \
        WAITSEQ;                                                                    \
    }

#define W0B do { VMWAIT0; RBARRIER; SCHEDB; } while (0)
#define WN do { } while (0)

#pragma unroll 1
    for (int t = 0; t < 31; ++t) {
        DO_PHASE(t, 1, W0B)
    }
    DO_PHASE(31, 0, WN)   // last tile: no staging, no trailing barrier
#undef DO_PHASE
#undef STAGE_ISSUE
#undef W0B
#undef WN

    // argmin across the 16 centroid-columns within each 16-lane group
    // (masks < 16 keep lg fixed); numpy tie-break: smaller k
#pragma unroll
    for (int r = 0; r < 4; ++r) {
        float bv = best[r]; int bi = bk[r];
#pragma unroll
        for (int m = 1; m < 16; m <<= 1) {
            float ov = __shfl_xor(bv, m);
            int oi = __shfl_xor(bi, m);
            if (ov < bv || (ov == bv && oi < bi)) { bv = ov; bi = oi; }
        }
        best[r] = bv; bk[r] = bi;
    }

    // D layout (m89-verified): col = lane&15, row = (lane>>4)*4 + r
    float xnv[4];
#pragma unroll
    for (int r = 0; r < 4; ++r)
        xnv[r] = __shfl(xs, lg * 4 + r);   // xs of point (lg*4+r) lives in lane (lg*4+r)

    if (l15 == 0) {
#pragma unroll
        for (int r = 0; r < 4; ++r) {
            int p = p0 + lg * 4 + r;
            bestv[(size_t)kh * NPTS + p] = best[r];    // pre-xn partial min
            bkv[(size_t)kh * NPTS + p] = bk[r];
            if (kh == 0) xn_arr[p] = xnv[r];
        }
    }
}

// ---------------- kernel 2: merge halves + per-batch stats + histogram + normalize ----------------
__global__ void finalize_kernel(const float* __restrict__ bestv, const int* __restrict__ bkv,
                                const float* __restrict__ xn_arr,
                                const float* __restrict__ weights, float* __restrict__ out) {
    __shared__ float dS[NN];      // merged min distances
    __shared__ int   bkS[NN];     // merged argmin
    __shared__ float red[1024];
    __shared__ int hist[KK];
    __shared__ float bc[2];       // mean, thr
    const int b = blockIdx.x;
    const int tid = threadIdx.x;

    // merge the two k-halves (strict <: half-0 ks all smaller -> numpy first-min),
    // then sq = xn + best, d = sqrt(max(sq,0))  — R9/R13-validated arithmetic order.
    float s = 0.f;
#pragma unroll
    for (int j = 0; j < NN / 1024; ++j) {
        int i = tid + 1024 * j;
        size_t gi = (size_t)b * NN + i;
        float b0 = bestv[gi], b1 = bestv[NPTS + gi];
        int k0 = bkv[gi], k1 = bkv[NPTS + gi];
        float bm = b0; int km = k0;
        if (b1 < bm) { bm = b1; km = k1; }
        float d = sqrtf(fmaxf(xn_arr[gi] + bm, 0.f));
        dS[i] = d; bkS[i] = km;
        s += d;
    }

    // pass A: mean (two-pass std to match numpy numerics)
    red[tid] = s;
    __syncthreads();
    for (int off = 512; off > 0; off >>= 1) {
        if (tid < off) red[tid] += red[tid + off];
        __syncthreads();
    }
    if (tid == 0) bc[0] = red[0] / (float)NN;
    __syncthreads();
    const float mean = bc[0];

    // pass B: sum of squared deviations -> thr = mean + std(ddof=1)
    float ss = 0.f;
#pragma unroll
    for (int j = 0; j < NN / 1024; ++j) {
        float v = dS[tid + 1024 * j] - mean;
        ss += v * v;
    }
    red[tid] = ss;
    __syncthreads();
    for (int off = 512; off > 0; off >>= 1) {
        if (tid < off) red[tid] += red[tid + off];
        __syncthreads();
    }
    if (tid == 0) bc[1] = mean + sqrtf(red[0] / (float)(NN - 1));

    // histogram of masked assignments
    hist[tid] = 0;
    __syncthreads();
    const float thr = bc[1];
#pragma unroll
    for (int j = 0; j < NN / 1024; ++j) {
        int i = tid + 1024 * j;
        if (dS[i] < thr) atomicAdd(&hist[bkS[i]], 1);
    }
    __syncthreads();

    // asmk = counts*weights; L2-normalize the row (one k per thread)
    const float a = (float)hist[tid] * weights[tid];
    red[tid] = a * a;
    __syncthreads();
    for (int off = 512; off > 0; off >>= 1) {
        if (tid < off) red[tid] += red[tid + off];
        __syncthreads();
    }
    const float norm = sqrtf(red[0]);
    const float scale = 1.f / fmaxf(norm, 1e-12f);
    out[(size_t)b * KK + tid] = a * scale;
}

extern "C" void kernel_launch(void* const* d_in, const int* in_sizes, int n_in,
                              void* d_out, int out_size, void* d_ws, size_t ws_size,
                              hipStream_t stream) {
    const float* x = (const float*)d_in[0];
    const float* cent = (const float*)d_in[1];
    const float* weights = (const float*)d_in[2];
    float* out = (float*)d_out;

    char* ws = (char*)d_ws;
    float* bestv  = (float*)(ws + 0);          // [2][NPTS]  512 KB
    int*   bkv    = (int*)  (ws + 524288);     // [2][NPTS]  512 KB
    float* xn_arr = (float*)(ws + 1048576);    // [NPTS]     256 KB
    float* cn     = (float*)(ws + 1310720);    // [KK]         4 KB
    uint4* cfh    = (uint4*)(ws + 1314816);    // 256 KB
    uint4* cfl    = (uint4*)(ws + 1576960);    // 256 KB

    prep_kernel<<<320, 256, 0, stream>>>(cent, cfh, cfl, cn);
    assign_mfma11<<<NPTS / 32, 256, 0, stream>>>(x, cfh, cfl, cn, bestv, bkv, xn_arr);
    finalize_kernel<<<BB, 1024, 0, stream>>>(bestv, bkv, xn_arr, weights, out);
}

// Round 17
// 75.106 us; speedup vs baseline: 2.2249x; 1.0325x over previous
//
#include <hip/hip_runtime.h>
#include <math.h>

#define BB 16
#define NN 4096
#define DD 128
#define KK 1024
#define NPTS (BB*NN)

typedef _Float16 half8 __attribute__((ext_vector_type(8)));
typedef float f32x4 __attribute__((ext_vector_type(4)));

static __device__ __forceinline__ uint pack2(float a, float b) {
    _Float16 ha = (_Float16)a, hb = (_Float16)b;
    unsigned short ua = __builtin_bit_cast(unsigned short, ha);
    unsigned short ub = __builtin_bit_cast(unsigned short, hb);
    return (uint)ua | ((uint)ub << 16);
}

typedef __attribute__((address_space(1))) const void as1_void;
typedef __attribute__((address_space(3))) void as3_void;
static __device__ __forceinline__ void gld16(const void* g, void* l) {
    // async global->LDS, 16B/lane; LDS dest = uniform base + lane*16 (HW rule)
    __builtin_amdgcn_global_load_lds((as1_void*)g, (as3_void*)l, 16, 0, 0);
}

#define VMWAIT2 asm volatile("s_waitcnt vmcnt(2)" ::: "memory")
#define VMWAIT0 asm volatile("s_waitcnt vmcnt(0)" ::: "memory")
#define LGKM0   asm volatile("s_waitcnt lgkmcnt(0)" ::: "memory")
#define RBARRIER do { __builtin_amdgcn_s_barrier(); asm volatile("" ::: "memory"); } while (0)
#define SCHEDB  __builtin_amdgcn_sched_barrier(0)

// ---------------- kernel 0 (fused): centroid fragments + squared norms ----------------
// Blocks [0,64): pre-permute centroids into 16x16x32 B-fragment order
//   fragment (nt, c, lane) = cent row (nt*16 + (lane&15)), d in [c*32+(lane>>4)*8, +8),
//   split fp16 hi + (lo*1024), packed uint4 (HW-verified layout, R12-R16 pass).
// Blocks [64,320): cn[row] = ||c_row||^2 in double (wave per row).
__global__ void prep_kernel(const float* __restrict__ cent,
                            uint4* __restrict__ cfh, uint4* __restrict__ cfl,
                            float* __restrict__ cnorm) {
    if (blockIdx.x < 64) {
        const int gid = blockIdx.x * 256 + threadIdx.x;   // [0, 64*4*64) = 16384
        const int nt = gid >> 8;
        const int c = (gid >> 6) & 3;
        const int lane = gid & 63;
        const int row = nt * 16 + (lane & 15);
        const int d0 = c * 32 + (lane >> 4) * 8;
        const float* src = cent + (size_t)row * DD + d0;
        float v[8];
#pragma unroll
        for (int i = 0; i < 8; ++i) v[i] = src[i];
        float lo[8];
#pragma unroll
        for (int i = 0; i < 8; ++i) {
            _Float16 h = (_Float16)v[i];
            lo[i] = (v[i] - (float)h) * 1024.f;
        }
        uint4 h4, l4;
        h4.x = pack2(v[0], v[1]); h4.y = pack2(v[2], v[3]);
        h4.z = pack2(v[4], v[5]); h4.w = pack2(v[6], v[7]);
        l4.x = pack2(lo[0], lo[1]); l4.y = pack2(lo[2], lo[3]);
        l4.z = pack2(lo[4], lo[5]); l4.w = pack2(lo[6], lo[7]);
        cfh[gid] = h4;
        cfl[gid] = l4;
    } else {
        const int w = threadIdx.x >> 6, lane = threadIdx.x & 63;
        const int row = (blockIdx.x - 64) * 4 + w;
        float2 v = ((const float2*)(cent + (size_t)row * DD))[lane];
        double s = (double)v.x * v.x + (double)v.y * v.y;
#pragma unroll
        for (int m = 1; m < 64; m <<= 1) s += __shfl_xor(s, m);
        if (lane == 0) cnorm[row] = (float)s;
    }
}

// ---------------- kernel 1: nearest-centroid, 3-slot ring, counted vmcnt(2), 6 blocks/CU ----------------
// 2048 blocks x 4 waves; block = (pblk = bid>>1, kh = bid&1). Wave w owns points
// [pblk*64 + w*16, +16); block scans the 32 16-cent tiles of k-half kh.
// LDS = 3-slot ring (24KB) + cnS half (2KB) = 26.6KB -> 6 blocks/CU (159.7KB).
// VGPR ~40-52 (R16-verified) -> 24 waves/CU register-legal.
// Protocol (counted lookahead, R12-proven): phase p reads slot p%3 (stage p),
// issues stage p+2 into slot (p+2)%3 (its readers passed the p-1 barrier),
// ends with vmcnt(2) + barrier: stage p+1's loads landed, stage p+2 in flight.
// Loop unrolled x3 so all slot indices are compile-time constants.
__launch_bounds__(256, 4)
__global__ void assign_mfma12(const float* __restrict__ x,
                              const uint4* __restrict__ cfh, const uint4* __restrict__ cfl,
                              const float* __restrict__ cn,
                              float* __restrict__ bestv, int* __restrict__ bkv,
                              float* __restrict__ xn_arr) {
    __shared__ uint4 ring[3][8][64];   // [slot][frag-row: 0-3 hi(c), 4-7 lo(c)][lane]
    __shared__ float cnS[KK / 2];

    const int tid = threadIdx.x;
    const int lane = tid & 63;
    const int w = tid >> 6;
    const int l15 = lane & 15;
    const int lg = lane >> 4;          // k-group 0..3
    const int kh = blockIdx.x & 1;
    const int pblk = blockIdx.x >> 1;
    const int p0 = pblk * 64 + w * 16;

#define STAGE_ISSUE(S, SSLOT)                                                       \
    { const size_t fb_ = ((size_t)(kh * 32 + (S)) * 4 + w) * 64 + lane;             \
      gld16(cfh + fb_, &ring[SSLOT][w][0]);                                         \
      gld16(cfl + fb_, &ring[SSLOT][w + 4][0]); }

    // prologue: issue stages 0,1 first (they fly under the cn/x loads)
    STAGE_ISSUE(0, 0)
    STAGE_ISSUE(1, 1)

    // this half's cn -> LDS (512 floats; consumed in epilogues)
    ((float2*)cnS)[tid] = ((const float2*)(cn + kh * (KK / 2)))[tid];

    // A fragments: lane covers row l15, k = c*32 + lg*8 + i (same split as R3-R16)
    half8 ahi[4], alo[4];
    float xs = 0.f;
    const float4* xrow = (const float4*)(x + (size_t)(p0 + l15) * DD);
#pragma unroll
    for (int c = 0; c < 4; ++c) {
        float4 v0 = xrow[c * 8 + lg * 2];
        float4 v1 = xrow[c * 8 + lg * 2 + 1];
        float vv[8] = {v0.x, v0.y, v0.z, v0.w, v1.x, v1.y, v1.z, v1.w};
#pragma unroll
        for (int i = 0; i < 8; ++i) {
            _Float16 h = (_Float16)vv[i];
            ahi[c][i] = h;
            alo[c][i] = (_Float16)((vv[i] - (float)h) * 1024.f);
            xs = fmaf(vv[i], vv[i], xs);
        }
    }
    // lanes {l15, l15+16, l15+32, l15+48} hold disjoint k-quarters of row l15
    xs += __shfl_xor(xs, 16);
    xs += __shfl_xor(xs, 32);          // every lane: ||x_{l15}||^2

    float best[4];
    int bk[4];
#pragma unroll
    for (int r = 0; r < 4; ++r) { best[r] = INFINITY; bk[r] = 0; }

    f32x4 zero4;                       // persistent zero C-in for MFMA chain heads
#pragma unroll
    for (int i = 0; i < 4; ++i) zero4[i] = 0.f;

    VMWAIT0;    // stages 0,1 + x + cn loads all landed (prologue-only full drain)
    LGKM0;      // own cnS ds_write done
    RBARRIER;   // all waves: stages 0,1 + cnS visible
    SCHEDB;

#define DO_PHASE(NT, SLOT, SST, SSLOT, DOSTG, WAITSEQ)                              \
    {                                                                               \
        /* chunk 1: hi fragments -> hh chain + alo*bh half of cr (R13/R14 order) */ \
        uint4 b0 = ring[SLOT][0][lane], b1 = ring[SLOT][1][lane];                   \
        uint4 b2 = ring[SLOT][2][lane], b3 = ring[SLOT][3][lane];                   \
        if (DOSTG) STAGE_ISSUE(SST, SSLOT)                                          \
        f32x4 hh, cr;                                                               \
        __builtin_amdgcn_s_setprio(1);                                              \
        hh = __builtin_amdgcn_mfma_f32_16x16x32_f16(ahi[0], __builtin_bit_cast(half8, b0), zero4, 0, 0, 0); \
        cr = __builtin_amdgcn_mfma_f32_16x16x32_f16(alo[0], __builtin_bit_cast(half8, b0), zero4, 0, 0, 0); \
        hh = __builtin_amdgcn_mfma_f32_16x16x32_f16(ahi[1], __builtin_bit_cast(half8, b1), hh, 0, 0, 0);    \
        cr = __builtin_amdgcn_mfma_f32_16x16x32_f16(alo[1], __builtin_bit_cast(half8, b1), cr, 0, 0, 0);    \
        hh = __builtin_amdgcn_mfma_f32_16x16x32_f16(ahi[2], __builtin_bit_cast(half8, b2), hh, 0, 0, 0);    \
        cr = __builtin_amdgcn_mfma_f32_16x16x32_f16(alo[2], __builtin_bit_cast(half8, b2), cr, 0, 0, 0);    \
        hh = __builtin_amdgcn_mfma_f32_16x16x32_f16(ahi[3], __builtin_bit_cast(half8, b3), hh, 0, 0, 0);    \
        cr = __builtin_amdgcn_mfma_f32_16x16x32_f16(alo[3], __builtin_bit_cast(half8, b3), cr, 0, 0, 0);    \
        __builtin_amdgcn_s_setprio(0);                                              \
        /* chunk 2: lo fragments (reuse b0..b3) -> ahi*bl half of cr */             \
        b0 = ring[SLOT][4][lane]; b1 = ring[SLOT][5][lane];                         \
        b2 = ring[SLOT][6][lane]; b3 = ring[SLOT][7][lane];                         \
        __builtin_amdgcn_s_setprio(1);                                              \
        cr = __builtin_amdgcn_mfma_f32_16x16x32_f16(ahi[0], __builtin_bit_cast(half8, b0), cr, 0, 0, 0);    \
        cr = __builtin_amdgcn_mfma_f32_16x16x32_f16(ahi[1], __builtin_bit_cast(half8, b1), cr, 0, 0, 0);    \
        cr = __builtin_amdgcn_mfma_f32_16x16x32_f16(ahi[2], __builtin_bit_cast(half8, b2), cr, 0, 0, 0);    \
        cr = __builtin_amdgcn_mfma_f32_16x16x32_f16(ahi[3], __builtin_bit_cast(half8, b3), cr, 0, 0, 0);    \
        __builtin_amdgcn_s_setprio(0);                                              \
        {   const float cnv_ = cnS[(NT) * 16 + l15];                                \
            const int kcur_ = (kh * 32 + (NT)) * 16 + l15;                          \
            _Pragma("unroll")                                                       \
            for (int r = 0; r < 4; ++r) {                                           \
                float v_ = cnv_ - 2.f * hh[r] - 0.001953125f * cr[r];               \
                if (v_ < best[r]) { best[r] = v_; bk[r] = kcur_; }                  \
            }                                                                       \
        }                                                                           \
        WAITSEQ;                                                                    \
    }

#define W2B do { VMWAIT2; RBARRIER; SCHEDB; } while (0)
#define W0B do { VMWAIT0; RBARRIER; SCHEDB; } while (0)
#define WN do { } while (0)

    // phases 0..29 (x3 unroll -> static slots); phase p issues stage p+2
#pragma unroll 1
    for (int t = 0; t < 30; t += 3) {
        DO_PHASE(t + 0, 0, t + 2, 2, 1, W2B)
        DO_PHASE(t + 1, 1, t + 3, 0, 1, W2B)
        DO_PHASE(t + 2, 2, t + 4, 1, 1, W2B)
    }
    // tail: stage 31 (issued at phase 29, slot 1) still in flight
    DO_PHASE(30, 0, 0, 0, 0, W0B)   // drain: stage 31 landed
    DO_PHASE(31, 1, 0, 0, 0, WN)    // last tile, no barrier
#undef DO_PHASE
#undef STAGE_ISSUE
#undef W2B
#undef W0B
#undef WN

    // argmin across the 16 centroid-columns within each 16-lane group
    // (masks < 16 keep lg fixed); numpy tie-break: smaller k
#pragma unroll
    for (int r = 0; r < 4; ++r) {
        float bv = best[r]; int bi = bk[r];
#pragma unroll
        for (int m = 1; m < 16; m <<= 1) {
            float ov = __shfl_xor(bv, m);
            int oi = __shfl_xor(bi, m);
            if (ov < bv || (ov == bv && oi < bi)) { bv = ov; bi = oi; }
        }
        best[r] = bv; bk[r] = bi;
    }

    // D layout (m89-verified): col = lane&15, row = (lane>>4)*4 + r
    float xnv[4];
#pragma unroll
    for (int r = 0; r < 4; ++r)
        xnv[r] = __shfl(xs, lg * 4 + r);   // xs of point (lg*4+r) lives in lane (lg*4+r)

    if (l15 == 0) {
#pragma unroll
        for (int r = 0; r < 4; ++r) {
            int p = p0 + lg * 4 + r;
            bestv[(size_t)kh * NPTS + p] = best[r];    // pre-xn partial min
            bkv[(size_t)kh * NPTS + p] = bk[r];
            if (kh == 0) xn_arr[p] = xnv[r];
        }
    }
}

// ---------------- kernel 2: merge halves + per-batch stats + histogram + normalize ----------------
__global__ void finalize_kernel(const float* __restrict__ bestv, const int* __restrict__ bkv,
                                const float* __restrict__ xn_arr,
                                const float* __restrict__ weights, float* __restrict__ out) {
    __shared__ float dS[NN];      // merged min distances
    __shared__ int   bkS[NN];     // merged argmin
    __shared__ float red[1024];
    __shared__ int hist[KK];
    __shared__ float bc[2];       // mean, thr
    const int b = blockIdx.x;
    const int tid = threadIdx.x;

    // merge the two k-halves (strict <: half-0 ks all smaller -> numpy first-min),
    // then sq = xn + best, d = sqrt(max(sq,0))  — R9/R13-validated arithmetic order.
    float s = 0.f;
#pragma unroll
    for (int j = 0; j < NN / 1024; ++j) {
        int i = tid + 1024 * j;
        size_t gi = (size_t)b * NN + i;
        float b0 = bestv[gi], b1 = bestv[NPTS + gi];
        int k0 = bkv[gi], k1 = bkv[NPTS + gi];
        float bm = b0; int km = k0;
        if (b1 < bm) { bm = b1; km = k1; }
        float d = sqrtf(fmaxf(xn_arr[gi] + bm, 0.f));
        dS[i] = d; bkS[i] = km;
        s += d;
    }

    // pass A: mean (two-pass std to match numpy numerics)
    red[tid] = s;
    __syncthreads();
    for (int off = 512; off > 0; off >>= 1) {
        if (tid < off) red[tid] += red[tid + off];
        __syncthreads();
    }
    if (tid == 0) bc[0] = red[0] / (float)NN;
    __syncthreads();
    const float mean = bc[0];

    // pass B: sum of squared deviations -> thr = mean + std(ddof=1)
    float ss = 0.f;
#pragma unroll
    for (int j = 0; j < NN / 1024; ++j) {
        float v = dS[tid + 1024 * j] - mean;
        ss += v * v;
    }
    red[tid] = ss;
    __syncthreads();
    for (int off = 512; off > 0; off >>= 1) {
        if (tid < off) red[tid] += red[tid + off];
        __syncthreads();
    }
    if (tid == 0) bc[1] = mean + sqrtf(red[0] / (float)(NN - 1));

    // histogram of masked assignments
    hist[tid] = 0;
    __syncthreads();
    const float thr = bc[1];
#pragma unroll
    for (int j = 0; j < NN / 1024; ++j) {
        int i = tid + 1024 * j;
        if (dS[i] < thr) atomicAdd(&hist[bkS[i]], 1);
    }
    __syncthreads();

    // asmk = counts*weights; L2-normalize the row (one k per thread)
    const float a = (float)hist[tid] * weights[tid];
    red[tid] = a * a;
    __syncthreads();
    for (int off = 512; off > 0; off >>= 1) {
        if (tid < off) red[tid] += red[tid + off];
        __syncthreads();
    }
    const float norm = sqrtf(red[0]);
    const float scale = 1.f / fmaxf(norm, 1e-12f);
    out[(size_t)b * KK + tid] = a * scale;
}

extern "C" void kernel_launch(void* const* d_in, const int* in_sizes, int n_in,
                              void* d_out, int out_size, void* d_ws, size_t ws_size,
                              hipStream_t stream) {
    const float* x = (const float*)d_in[0];
    const float* cent = (const float*)d_in[1];
    const float* weights = (const float*)d_in[2];
    float* out = (float*)d_out;

    char* ws = (char*)d_ws;
    float* bestv  = (float*)(ws + 0);          // [2][NPTS]  512 KB
    int*   bkv    = (int*)  (ws + 524288);     // [2][NPTS]  512 KB
    float* xn_arr = (float*)(ws + 1048576);    // [NPTS]     256 KB
    float* cn     = (float*)(ws + 1310720);    // [KK]         4 KB
    uint4* cfh    = (uint4*)(ws + 1314816);    // 256 KB
    uint4* cfl    = (uint4*)(ws + 1576960);    // 256 KB

    prep_kernel<<<320, 256, 0, stream>>>(cent, cfh, cfl, cn);
    assign_mfma12<<<NPTS / 32, 256, 0, stream>>>(x, cfh, cfl, cn, bestv, bkv, xn_arr);
    finalize_kernel<<<BB, 1024, 0, stream>>>(bestv, bkv, xn_arr, weights, out);
}